// Round 1
// baseline (18066.174 us; speedup 1.0000x reference)
//
#include <hip/hip_runtime.h>
#include <math.h>

#define NPTS 100000
#define LKV 4
#define GYV 200
#define NBINS 40000   // GY*GY

// ---------- monotonic float<->uint encoding for atomicMax-based segment max ----
__device__ __forceinline__ unsigned fenc(float f) {
    unsigned u = __float_as_uint(f);
    return (u & 0x80000000u) ? ~u : (u | 0x80000000u);
}
__device__ __forceinline__ float fdec(unsigned u) {
    unsigned b = (u & 0x80000000u) ? (u & 0x7fffffffu) : ~u;
    return __uint_as_float(b);
}

// ---------- tile GEMM: 16 points x OD outputs, 256 threads (16 thr/pt) ----------
// thread t: p = t>>4, owns contiguous OD/16 outputs. in: LDS [16][KD]. out: [16][OD].
// MODE 0: out = acc + lb[o]
// MODE 1: out = relu( (acc + lb[o] - m[o]) * g[o]*rsqrt(v[o]+eps) + bb[o] )   (Linear+BN+ReLU)
// MODE 2: out = relu( acc + lb[o] )
template <int KD, int OD, int MODE>
__device__ __forceinline__ void tile_gemm(
    const float* __restrict__ W, const float* __restrict__ lb,
    const float* __restrict__ g, const float* __restrict__ bb,
    const float* __restrict__ m, const float* __restrict__ v,
    const float* __restrict__ in, float* out, int t)
{
    constexpr int OPT = OD / 16;
    static_assert(OPT >= 1, "OD must be >= 16");
    const int p = t >> 4, c = t & 15, o0 = c * OPT;
    const float* inp = in + p * KD;
    float acc[OPT];
#pragma unroll
    for (int j = 0; j < OPT; ++j) acc[j] = 0.f;
#pragma unroll 4
    for (int k = 0; k < KD; ++k) {
        float a = inp[k];
        const float* wr = W + k * OD + o0;
        if constexpr (OPT % 4 == 0) {
#pragma unroll
            for (int j4 = 0; j4 < OPT / 4; ++j4) {
                float4 w4 = reinterpret_cast<const float4*>(wr)[j4];
                acc[j4 * 4 + 0] += a * w4.x;
                acc[j4 * 4 + 1] += a * w4.y;
                acc[j4 * 4 + 2] += a * w4.z;
                acc[j4 * 4 + 3] += a * w4.w;
            }
        } else {
#pragma unroll
            for (int j = 0; j < OPT; ++j) acc[j] += a * wr[j];
        }
    }
#pragma unroll
    for (int j = 0; j < OPT; ++j) {
        int o = o0 + j;
        float y = acc[j] + lb[o];
        if constexpr (MODE == 1) {
            float s = g[o] * rsqrtf(v[o] + 1e-5f);
            y = (y - m[o]) * s + bb[o];
            y = fmaxf(y, 0.f);
        } else if constexpr (MODE == 2) {
            y = fmaxf(y, 0.f);
        }
        out[p * OD + o] = y;
    }
}

// ---------- K0: zero seg/pix pool regions (as uint) + histogram bins ------------
__global__ void kZ(unsigned* __restrict__ seg_u, unsigned* __restrict__ pix_u,
                   int* __restrict__ count)
{
    size_t idx = (size_t)blockIdx.x * 256 + threadIdx.x;
    const size_t SEG = (size_t)NPTS * 256;
    if (idx < SEG)            seg_u[idx] = 0u;
    else if (idx < 2 * SEG)   pix_u[idx - SEG] = 0u;
    else if (idx < 2 * SEG + NBINS) count[idx - 2 * SEG] = 0;
}

// ---------- K1: keys + histogram ------------------------------------------------
__global__ void kH(const int* __restrict__ xy, int* __restrict__ keys,
                   int* __restrict__ count)
{
    int i = blockIdx.x * 256 + threadIdx.x;
    if (i < NPTS) {
        int key = xy[i * 2] * GYV + xy[i * 2 + 1];
        keys[i] = key;
        atomicAdd(count + key, 1);
    }
}

// ---------- K2: prefix-scan of present flags over 40000 bins (1 block) ----------
// rank[key] = unq_inv index; unq_keys[rank] = key (sorted since keys ascend).
__global__ __launch_bounds__(1024) void kScan(
    const int* __restrict__ count, int* __restrict__ rank,
    int* __restrict__ unqk, int* __restrict__ total)
{
    __shared__ int swcnt[16];
    __shared__ int carry_s;
    const int t = threadIdx.x, lane = t & 63, wid = t >> 6;
    if (t == 0) carry_s = 0;
    for (int chunk = 0; chunk < 40; ++chunk) {
        __syncthreads();   // protects swcnt reuse across chunks
        int idx = chunk * 1024 + t;
        int pres = (idx < NBINS && count[idx] > 0) ? 1 : 0;
        unsigned long long mask = __ballot(pres);
        int lanepre = __popcll(mask & ((1ull << lane) - 1ull));
        if (lane == 0) swcnt[wid] = __popcll(mask);
        __syncthreads();
        if (t == 0) {
            int s = carry_s;
            for (int w = 0; w < 16; ++w) { int cn = swcnt[w]; swcnt[w] = s; s += cn; }
            carry_s = s;
        }
        __syncthreads();
        if (pres) { int e = swcnt[wid] + lanepre; rank[idx] = e; unqk[e] = idx; }
    }
    __syncthreads();
    if (t == 0) total[0] = carry_s;
}

// ---------- KU: unq output rows (padded rows use fill 40000 -> [0,200,0]) -------
__global__ void kU(const int* __restrict__ unqk, const int* __restrict__ total,
                   float* __restrict__ out_unq)
{
    int j = blockIdx.x * 256 + threadIdx.x;
    if (j < NPTS) {
        int k = (j < total[0]) ? unqk[j] : NBINS;
        out_unq[j * 3 + 0] = 0.f;
        out_unq[j * 3 + 1] = (float)(k / GYV);
        out_unq[j * 3 + 2] = (float)(k % GYV);
    }
}

// ---------- KA: PPmodel (BN->3xLin/BN/ReLU->Lin) + mlp pool-atomics + q ---------
__global__ __launch_bounds__(256) void kA(
    const float* __restrict__ pt_fea,
    const int* __restrict__ keys, const int* __restrict__ rank,
    const float* g0, const float* b0, const float* m0, const float* v0,
    const float* W1, const float* b1, const float* g1, const float* bb1, const float* m1, const float* v1,
    const float* W2, const float* b2, const float* g2, const float* bb2, const float* m2, const float* v2,
    const float* W3, const float* b3, const float* g3, const float* bb3, const float* m3, const float* v3,
    const float* W4, const float* b4,
    const float* Wq, const float* bq,
    float* __restrict__ q_out, unsigned* __restrict__ seg_u)
{
    __shared__ float bufA[16 * 256];
    __shared__ float bufB[16 * 256];
    __shared__ int invs[16];
    const int t = threadIdx.x;
    const int base = blockIdx.x * 16;
    if (t < 48) {   // load + input BN (3 dims)
        int p = t / 3, c = t - p * 3;
        float x = pt_fea[(base + p) * 3 + c];
        float s = g0[c] * rsqrtf(v0[c] + 1e-5f);
        bufA[p * 3 + c] = (x - m0[c]) * s + b0[c];
    }
    if (t < 16) invs[t] = rank[keys[base + t]];
    __syncthreads();
    tile_gemm<3, 64, 1>(W1, b1, g1, bb1, m1, v1, bufA, bufB, t);  __syncthreads();
    tile_gemm<64, 128, 1>(W2, b2, g2, bb2, m2, v2, bufB, bufA, t); __syncthreads();
    tile_gemm<128, 256, 1>(W3, b3, g3, bb3, m3, v3, bufA, bufB, t); __syncthreads();
    tile_gemm<256, 256, 0>(W4, b4, nullptr, nullptr, nullptr, nullptr, bufB, bufA, t); // mlp
    __syncthreads();
    {   // segment-max(mlp) scatter into seg_pooled region (staged as encoded uints)
        const int p = t >> 4, c = t & 15;
        unsigned* dst = seg_u + (size_t)invs[p] * 256 + c * 16;
        const float* src = bufA + p * 256 + c * 16;
#pragma unroll
        for (int j = 0; j < 16; ++j) atomicMax(dst + j, fenc(src[j]));
    }
    // q = mlp @ Wq + bq, straight to global (each thread owns 16 contiguous floats)
    tile_gemm<256, 256, 0>(Wq, bq, nullptr, nullptr, nullptr, nullptr,
                           bufA, q_out + (size_t)base * 256, t);
}

// ---------- KC1: decode pooled-mlp, compression head, re-zero region ------------
__global__ __launch_bounds__(256) void kC1(
    unsigned* __restrict__ seg_u, const int* __restrict__ total,
    const float* __restrict__ W128, const float* __restrict__ b128,
    const float* __restrict__ Wc, const float* __restrict__ bc,
    float* __restrict__ out_proc)
{
    __shared__ float pooled[16 * 256];
    __shared__ float ori[16 * 128];
    const int t = threadIdx.x, p = t >> 4, c = t & 15;
    const int j0 = blockIdx.x * 16;
    const int tot = total[0];
    {
        const int j = j0 + p;
        unsigned* src = seg_u + (size_t)j * 256 + c * 16;
        float* dst = pooled + p * 256 + c * 16;
        if (j < tot) {
#pragma unroll
            for (int jj = 0; jj < 16; ++jj) { dst[jj] = fdec(src[jj]); src[jj] = 0u; }
        } else {
            // invalid segment: pool=0 -> ori=b128 -> processed=relu(b128@Wc+bc)
#pragma unroll
            for (int jj = 0; jj < 16; ++jj) dst[jj] = 0.f;
        }
    }
    __syncthreads();
    tile_gemm<256, 128, 0>(W128, b128, nullptr, nullptr, nullptr, nullptr, pooled, ori, t);
    __syncthreads();
    tile_gemm<128, 16, 2>(Wc, bc, nullptr, nullptr, nullptr, nullptr,
                          ori, out_proc + (size_t)j0 * 16, t);
}

// ---------- KP: pix pool atomics + unq_inv output (1 block per point) -----------
__global__ void kP(const float* __restrict__ pixfea,
                   const int* __restrict__ keys, const int* __restrict__ rank,
                   unsigned* __restrict__ pix_u, float* __restrict__ out_inv)
{
    size_t idx = (size_t)blockIdx.x * 256 + threadIdx.x;
    int i = (int)(idx >> 8), c = (int)(idx & 255);
    int inv = rank[keys[i]];
    atomicMax(pix_u + (size_t)inv * 256 + c, fenc(pixfea[idx]));
    if (c == 0) out_inv[i] = (float)inv;
}

// ---------- KB: fused MHA (L=4, online softmax) + sam pool atomics --------------
__global__ __launch_bounds__(256) void kB(
    const float* __restrict__ segfea, const float* __restrict__ q_in,
    const int* __restrict__ keys, const int* __restrict__ rank,
    const float* __restrict__ Wk, const float* __restrict__ bk,
    const float* __restrict__ Wv, const float* __restrict__ bv,
    const float* __restrict__ Wo, const float* __restrict__ bo,
    unsigned* __restrict__ seg_u)
{
    __shared__ float qb[16 * 256];
    __shared__ float segl[16 * 256];
    __shared__ float kv[16 * 256];
    __shared__ float part[16 * 4 * 4];
    __shared__ float mbuf[64], dbuf[64], abuf[64], wbuf[64];
    __shared__ int invs[16];
    const int t = threadIdx.x, p = t >> 4, c = t & 15, ht = c >> 2;
    const int base = blockIdx.x * 16;
    {   // load q tile
        const float4* src = reinterpret_cast<const float4*>(q_in + (size_t)(base + p) * 256 + c * 16);
        float4* dst = reinterpret_cast<float4*>(qb + p * 256 + c * 16);
#pragma unroll
        for (int j = 0; j < 4; ++j) dst[j] = src[j];
    }
    if (t < 16) invs[t] = rank[keys[base + t]];
    if (t < 64) { mbuf[t] = -INFINITY; dbuf[t] = 0.f; }
    float acc[16];
#pragma unroll
    for (int j = 0; j < 16; ++j) acc[j] = 0.f;

    for (int l = 0; l < LKV; ++l) {
        __syncthreads();   // prev iter done with segl/kv
        {   // load segfea[:, l, :]
            const float4* s4 = reinterpret_cast<const float4*>(
                segfea + ((size_t)(base + p) * LKV + l) * 256 + c * 16);
            float4* d4 = reinterpret_cast<float4*>(segl + p * 256 + c * 16);
#pragma unroll
            for (int j = 0; j < 4; ++j) d4[j] = s4[j];
        }
        __syncthreads();
        tile_gemm<256, 256, 0>(Wk, bk, nullptr, nullptr, nullptr, nullptr, segl, kv, t);
        __syncthreads();
        {   // partial score dot: 16 thr/pt = (head h, quarter r)
            int h = c >> 2, r = c & 3;
            float s = 0.f;
            int off = p * 256 + h * 64 + r * 16;
#pragma unroll
            for (int d = 0; d < 16; ++d) s += qb[off + d] * kv[off + d];
            part[(p * 4 + h) * 4 + r] = s;
        }
        __syncthreads();
        if (c < 4) {   // online-softmax state update, one thread per (p, head)
            int i4 = p * 4 + c;
            float s = (part[i4 * 4] + part[i4 * 4 + 1] + part[i4 * 4 + 2] + part[i4 * 4 + 3]) * 0.125f;
            float mo = mbuf[i4];
            float mn = fmaxf(mo, s);
            float al = __expf(mo - mn);
            float w  = __expf(s - mn);
            mbuf[i4] = mn;
            dbuf[i4] = dbuf[i4] * al + w;
            abuf[i4] = al; wbuf[i4] = w;
        }
        __syncthreads();
        tile_gemm<256, 256, 0>(Wv, bv, nullptr, nullptr, nullptr, nullptr, segl, kv, t); // overwrite k with v
        __syncthreads();
        {   // attnv rescale-accumulate (thread's 16 outputs are within one head)
            float al = abuf[p * 4 + ht], w = wbuf[p * 4 + ht];
            const float* vv = kv + p * 256 + c * 16;
#pragma unroll
            for (int j = 0; j < 16; ++j) acc[j] = acc[j] * al + w * vv[j];
        }
    }
    // normalize, put attnv in kv for the Wo GEMM
    {
        float dn = 1.f / dbuf[p * 4 + ht];
        float* vv = kv + p * 256 + c * 16;
#pragma unroll
        for (int j = 0; j < 16; ++j) vv[j] = acc[j] * dn;
    }
    __syncthreads();
    tile_gemm<256, 256, 0>(Wo, bo, nullptr, nullptr, nullptr, nullptr, kv, segl, t); // sam
    {   // segment-max(sam) atomics
        unsigned* dst = seg_u + (size_t)invs[p] * 256 + c * 16;
        const float* src = segl + p * 256 + c * 16;
#pragma unroll
        for (int j = 0; j < 16; ++j) atomicMax(dst + j, fenc(src[j]));
    }
}

// ---------- KC2: decode seg/pix pooled regions in place (valid rows only) -------
__global__ void kC2(unsigned* __restrict__ seg_u, unsigned* __restrict__ pix_u,
                    const int* __restrict__ total)
{
    size_t idx = (size_t)blockIdx.x * 256 + threadIdx.x;
    const size_t SEG = (size_t)NPTS * 256;
    int tot = total[0];
    unsigned* buf = (idx < SEG) ? seg_u : pix_u;
    size_t k = (idx < SEG) ? idx : (idx - SEG);
    int j = (int)(k >> 8);
    if (j < tot) buf[k] = __float_as_uint(fdec(buf[k]));
}

extern "C" void kernel_launch(void* const* d_in, const int* in_sizes, int n_in,
                              void* d_out, int out_size, void* d_ws, size_t ws_size,
                              hipStream_t stream)
{
    const float* pt_fea = (const float*)d_in[0];
    const int*   xy     = (const int*)d_in[1];
    const float* segfea = (const float*)d_in[2];
    const float* pixfea = (const float*)d_in[3];
    const float* g0 = (const float*)d_in[4],  *b0 = (const float*)d_in[5];
    const float* m0 = (const float*)d_in[6],  *v0 = (const float*)d_in[7];
    const float* g1 = (const float*)d_in[8],  *bb1 = (const float*)d_in[9];
    const float* m1 = (const float*)d_in[10], *v1 = (const float*)d_in[11];
    const float* g2 = (const float*)d_in[12], *bb2 = (const float*)d_in[13];
    const float* m2 = (const float*)d_in[14], *v2 = (const float*)d_in[15];
    const float* g3 = (const float*)d_in[16], *bb3 = (const float*)d_in[17];
    const float* m3 = (const float*)d_in[18], *v3 = (const float*)d_in[19];
    const float* W1 = (const float*)d_in[20], *b1 = (const float*)d_in[21];
    const float* W2 = (const float*)d_in[22], *b2 = (const float*)d_in[23];
    const float* W3 = (const float*)d_in[24], *b3 = (const float*)d_in[25];
    const float* W4 = (const float*)d_in[26], *b4 = (const float*)d_in[27];
    const float* Wq = (const float*)d_in[28], *bq = (const float*)d_in[29];
    const float* Wk = (const float*)d_in[30], *bk = (const float*)d_in[31];
    const float* Wv = (const float*)d_in[32], *bv = (const float*)d_in[33];
    const float* Wo = (const float*)d_in[34], *bo = (const float*)d_in[35];
    const float* W128 = (const float*)d_in[36], *b128 = (const float*)d_in[37];
    const float* Wc = (const float*)d_in[38], *bc = (const float*)d_in[39];

    // d_out layout (float32, outputs concatenated): unq[N,3] processed[N,16]
    // seg_pooled[N,256] pix_pooled[N,256] unq_inv[N]
    float* out = (float*)d_out;
    float* out_unq  = out;
    float* out_proc = out + (size_t)NPTS * 3;
    unsigned* seg_u = (unsigned*)(out + (size_t)NPTS * 19);
    unsigned* pix_u = (unsigned*)(out + (size_t)NPTS * 275);
    float* out_inv  = out + (size_t)NPTS * 531;

    // ws layout: q[N*256] f32, keys[N], rank[40000], count[40000], unqk[N], total[1]
    char* ws = (char*)d_ws;
    float* q_ws = (float*)ws;
    int* keys  = (int*)(ws + (size_t)NPTS * 256 * 4);
    int* rank  = keys + NPTS;
    int* count = rank + NBINS;
    int* unqk  = count + NBINS;
    int* total = unqk + NPTS;

    const int NB16 = NPTS / 16;                      // 6250
    const size_t ZTOT = 2 * (size_t)NPTS * 256 + NBINS;
    kZ<<<(int)((ZTOT + 255) / 256), 256, 0, stream>>>(seg_u, pix_u, count);
    kH<<<(NPTS + 255) / 256, 256, 0, stream>>>(xy, keys, count);
    kScan<<<1, 1024, 0, stream>>>(count, rank, unqk, total);
    kU<<<(NPTS + 255) / 256, 256, 0, stream>>>(unqk, total, out_unq);
    kA<<<NB16, 256, 0, stream>>>(pt_fea, keys, rank,
        g0, b0, m0, v0,
        W1, b1, g1, bb1, m1, v1,
        W2, b2, g2, bb2, m2, v2,
        W3, b3, g3, bb3, m3, v3,
        W4, b4, Wq, bq, q_ws, seg_u);
    kC1<<<NB16, 256, 0, stream>>>(seg_u, total, W128, b128, Wc, bc, out_proc);
    kP<<<NPTS, 256, 0, stream>>>(pixfea, keys, rank, pix_u, out_inv);
    kB<<<NB16, 256, 0, stream>>>(segfea, q_ws, keys, rank, Wk, bk, Wv, bv, Wo, bo, seg_u);
    kC2<<<2 * NPTS, 256, 0, stream>>>(seg_u, pix_u, total);
}

// Round 2
// 5320.335 us; speedup vs baseline: 3.3957x; 3.3957x over previous
//
#include <hip/hip_runtime.h>
#include <math.h>

#define NPTS 100000
#define LKV 4
#define GYV 200
#define NBINS 40000   // GY*GY

typedef __attribute__((ext_vector_type(8))) short bf16x8;
typedef __attribute__((ext_vector_type(4))) float f32x4;

// ---------- bf16 helpers (RNE) --------------------------------------------------
__device__ __forceinline__ unsigned short bfr(float f) {
    unsigned u = __float_as_uint(f);
    unsigned r = (u + 0x7fffu + ((u >> 16) & 1u)) >> 16;
    return (unsigned short)r;
}
__device__ __forceinline__ float fbf(unsigned short h) {
    return __uint_as_float(((unsigned)h) << 16);
}

// ---------- monotonic float<->uint encoding for atomicMax-based segment max ----
__device__ __forceinline__ unsigned fenc(float f) {
    unsigned u = __float_as_uint(f);
    return (u & 0x80000000u) ? ~u : (u | 0x80000000u);
}
__device__ __forceinline__ float fdec(unsigned u) {
    unsigned b = (u & 0x80000000u) ? (u & 0x7fffffffu) : ~u;
    return __uint_as_float(b);
}

// ---------- tile GEMM (fp32 VALU; used by kA / kC1) -----------------------------
// MODE 0: out=acc+lb | MODE 1: Lin+BN+ReLU | MODE 2: Lin+ReLU
// OB: true -> store bf16 (ushort*), false -> float*
template <int KD, int OD, int MODE, bool OB = false>
__device__ __forceinline__ void tile_gemm(
    const float* __restrict__ W, const float* __restrict__ lb,
    const float* __restrict__ g, const float* __restrict__ bb,
    const float* __restrict__ m, const float* __restrict__ v,
    const float* __restrict__ in, void* outv, int t)
{
    constexpr int OPT = OD / 16;
    const int p = t >> 4, c = t & 15, o0 = c * OPT;
    const float* inp = in + p * KD;
    float acc[OPT];
#pragma unroll
    for (int j = 0; j < OPT; ++j) acc[j] = 0.f;
#pragma unroll 4
    for (int k = 0; k < KD; ++k) {
        float a = inp[k];
        const float* wr = W + k * OD + o0;
        if constexpr (OPT % 4 == 0) {
#pragma unroll
            for (int j4 = 0; j4 < OPT / 4; ++j4) {
                float4 w4 = reinterpret_cast<const float4*>(wr)[j4];
                acc[j4 * 4 + 0] += a * w4.x;
                acc[j4 * 4 + 1] += a * w4.y;
                acc[j4 * 4 + 2] += a * w4.z;
                acc[j4 * 4 + 3] += a * w4.w;
            }
        } else {
#pragma unroll
            for (int j = 0; j < OPT; ++j) acc[j] += a * wr[j];
        }
    }
#pragma unroll
    for (int j = 0; j < OPT; ++j) {
        int o = o0 + j;
        float y = acc[j] + lb[o];
        if constexpr (MODE == 1) {
            float s = g[o] * rsqrtf(v[o] + 1e-5f);
            y = (y - m[o]) * s + bb[o];
            y = fmaxf(y, 0.f);
        } else if constexpr (MODE == 2) {
            y = fmaxf(y, 0.f);
        }
        if constexpr (OB) ((unsigned short*)outv)[p * OD + o] = bfr(y);
        else              ((float*)outv)[p * OD + o] = y;
    }
}

// ---------- K0: zero seg/pix pool regions (as uint) + histogram bins ------------
__global__ void kZ(unsigned* __restrict__ seg_u, unsigned* __restrict__ pix_u,
                   int* __restrict__ count)
{
    size_t idx = (size_t)blockIdx.x * 256 + threadIdx.x;
    const size_t SEG = (size_t)NPTS * 256;
    if (idx < SEG)            seg_u[idx] = 0u;
    else if (idx < 2 * SEG)   pix_u[idx - SEG] = 0u;
    else if (idx < 2 * SEG + NBINS) count[idx - 2 * SEG] = 0;
}

// ---------- K1: keys + histogram ------------------------------------------------
__global__ void kH(const int* __restrict__ xy, int* __restrict__ keys,
                   int* __restrict__ count)
{
    int i = blockIdx.x * 256 + threadIdx.x;
    if (i < NPTS) {
        int key = xy[i * 2] * GYV + xy[i * 2 + 1];
        keys[i] = key;
        atomicAdd(count + key, 1);
    }
}

// ---------- K2: prefix-scan of present flags over 40000 bins (1 block) ----------
__global__ __launch_bounds__(1024) void kScan(
    const int* __restrict__ count, int* __restrict__ rank,
    int* __restrict__ unqk, int* __restrict__ total)
{
    __shared__ int swcnt[16];
    __shared__ int carry_s;
    const int t = threadIdx.x, lane = t & 63, wid = t >> 6;
    if (t == 0) carry_s = 0;
    for (int chunk = 0; chunk < 40; ++chunk) {
        __syncthreads();
        int idx = chunk * 1024 + t;
        int pres = (idx < NBINS && count[idx] > 0) ? 1 : 0;
        unsigned long long mask = __ballot(pres);
        int lanepre = __popcll(mask & ((1ull << lane) - 1ull));
        if (lane == 0) swcnt[wid] = __popcll(mask);
        __syncthreads();
        if (t == 0) {
            int s = carry_s;
            for (int w = 0; w < 16; ++w) { int cn = swcnt[w]; swcnt[w] = s; s += cn; }
            carry_s = s;
        }
        __syncthreads();
        if (pres) { int e = swcnt[wid] + lanepre; rank[idx] = e; unqk[e] = idx; }
    }
    __syncthreads();
    if (t == 0) total[0] = carry_s;
}

// ---------- KU: unq output rows -------------------------------------------------
__global__ void kU(const int* __restrict__ unqk, const int* __restrict__ total,
                   float* __restrict__ out_unq)
{
    int j = blockIdx.x * 256 + threadIdx.x;
    if (j < NPTS) {
        int k = (j < total[0]) ? unqk[j] : NBINS;
        out_unq[j * 3 + 0] = 0.f;
        out_unq[j * 3 + 1] = (float)(k / GYV);
        out_unq[j * 3 + 2] = (float)(k % GYV);
    }
}

// ---------- KConv: fp32 weights -> bf16 fragment-order (B operand) --------------
// layout: wf[kt][ntile][quad][n16][8j]; element (k,n):
//   idx = ((((k>>5)*16 + (n>>4))*4 + ((k>>3)&3))*16 + (n&15))*8 + (k&7)
__global__ void kConv(const float* __restrict__ Wk, const float* __restrict__ Wv,
                      const float* __restrict__ Wo, unsigned short* __restrict__ wf)
{
    int gid = blockIdx.x * 256 + threadIdx.x;          // 3*65536 total
    int wsel = gid >> 16, r = gid & 65535;
    int k = r >> 8, n = r & 255;
    const float* W = (wsel == 0) ? Wk : (wsel == 1) ? Wv : Wo;
    int idx = ((((k >> 5) * 16 + (n >> 4)) * 4 + ((k >> 3) & 3)) * 16 + (n & 15)) * 8 + (k & 7);
    wf[wsel * 65536 + idx] = bfr(W[r]);
}

// ---------- KA: PPmodel + mlp pool-atomics + q (q stored bf16) ------------------
__global__ __launch_bounds__(256) void kA(
    const float* __restrict__ pt_fea,
    const int* __restrict__ keys, const int* __restrict__ rank,
    const float* g0, const float* b0, const float* m0, const float* v0,
    const float* W1, const float* b1, const float* g1, const float* bb1, const float* m1, const float* v1,
    const float* W2, const float* b2, const float* g2, const float* bb2, const float* m2, const float* v2,
    const float* W3, const float* b3, const float* g3, const float* bb3, const float* m3, const float* v3,
    const float* W4, const float* b4,
    const float* Wq, const float* bq,
    unsigned short* __restrict__ q_out, unsigned* __restrict__ seg_u)
{
    __shared__ float bufA[16 * 256];
    __shared__ float bufB[16 * 256];
    __shared__ int invs[16];
    const int t = threadIdx.x;
    const int base = blockIdx.x * 16;
    if (t < 48) {
        int p = t / 3, c = t - p * 3;
        float x = pt_fea[(base + p) * 3 + c];
        float s = g0[c] * rsqrtf(v0[c] + 1e-5f);
        bufA[p * 3 + c] = (x - m0[c]) * s + b0[c];
    }
    if (t < 16) invs[t] = rank[keys[base + t]];
    __syncthreads();
    tile_gemm<3, 64, 1>(W1, b1, g1, bb1, m1, v1, bufA, bufB, t);  __syncthreads();
    tile_gemm<64, 128, 1>(W2, b2, g2, bb2, m2, v2, bufB, bufA, t); __syncthreads();
    tile_gemm<128, 256, 1>(W3, b3, g3, bb3, m3, v3, bufA, bufB, t); __syncthreads();
    tile_gemm<256, 256, 0>(W4, b4, nullptr, nullptr, nullptr, nullptr, bufB, bufA, t); // mlp
    __syncthreads();
    {
        const int p = t >> 4, c = t & 15;
        unsigned* dst = seg_u + (size_t)invs[p] * 256 + c * 16;
        const float* src = bufA + p * 256 + c * 16;
#pragma unroll
        for (int j = 0; j < 16; ++j) atomicMax(dst + j, fenc(src[j]));
    }
    tile_gemm<256, 256, 0, true>(Wq, bq, nullptr, nullptr, nullptr, nullptr,
                                 bufA, q_out + (size_t)base * 256, t);
}

// ---------- KC1: decode pooled-mlp, compression head, re-zero region ------------
__global__ __launch_bounds__(256) void kC1(
    unsigned* __restrict__ seg_u, const int* __restrict__ total,
    const float* __restrict__ W128, const float* __restrict__ b128,
    const float* __restrict__ Wc, const float* __restrict__ bc,
    float* __restrict__ out_proc)
{
    __shared__ float pooled[16 * 256];
    __shared__ float ori[16 * 128];
    const int t = threadIdx.x, p = t >> 4, c = t & 15;
    const int j0 = blockIdx.x * 16;
    const int tot = total[0];
    {
        const int j = j0 + p;
        unsigned* src = seg_u + (size_t)j * 256 + c * 16;
        float* dst = pooled + p * 256 + c * 16;
        if (j < tot) {
#pragma unroll
            for (int jj = 0; jj < 16; ++jj) { dst[jj] = fdec(src[jj]); src[jj] = 0u; }
        } else {
#pragma unroll
            for (int jj = 0; jj < 16; ++jj) dst[jj] = 0.f;
        }
    }
    __syncthreads();
    tile_gemm<256, 128, 0>(W128, b128, nullptr, nullptr, nullptr, nullptr, pooled, ori, t);
    __syncthreads();
    tile_gemm<128, 16, 2>(Wc, bc, nullptr, nullptr, nullptr, nullptr,
                          ori, out_proc + (size_t)j0 * 16, t);
}

// ---------- KP: pix pool atomics + unq_inv output -------------------------------
__global__ void kP(const float* __restrict__ pixfea,
                   const int* __restrict__ keys, const int* __restrict__ rank,
                   unsigned* __restrict__ pix_u, float* __restrict__ out_inv)
{
    size_t idx = (size_t)blockIdx.x * 256 + threadIdx.x;
    int i = (int)(idx >> 8), c = (int)(idx & 255);
    int inv = rank[keys[i]];
    atomicMax(pix_u + (size_t)inv * 256 + c, fenc(pixfea[idx]));
    if (c == 0) out_inv[i] = (float)inv;
}

// ---------- KB: bf16-MFMA fused MHA + sam pool atomics --------------------------
// block = 16 points = 64 segfea rows; 4 waves; wave w owns cols [64w,64w+64) = head w.
__global__ __launch_bounds__(256) void kB(
    const float* __restrict__ segfea, const unsigned short* __restrict__ q_in,
    const int* __restrict__ keys, const int* __restrict__ rank,
    const unsigned short* __restrict__ wkf, const unsigned short* __restrict__ wvf,
    const unsigned short* __restrict__ wof,
    const float* __restrict__ bk, const float* __restrict__ bv,
    const float* __restrict__ bo,
    unsigned* __restrict__ seg_u)
{
    // A-operand LDS, fragment order: idx(row,k) = ((k>>5)*64 + row)*32 + ((k>>3)&3)*8 + (k&7)
    __shared__ __attribute__((aligned(16))) unsigned short x_lds[64 * 256];   // 32 KB
    __shared__ __attribute__((aligned(16))) unsigned short av_lds[16 * 256];  // 8 KB
    __shared__ int invs[16];
    const int t = threadIdx.x, w = t >> 6, lane = t & 63;
    const int quad = lane >> 4, c16 = lane & 15;
    const int base = blockIdx.x * 16;

    // ---- stage segfea rows (base*4 .. base*4+63) -> x_lds bf16 fragment order
    {
        const float4* gsrc = reinterpret_cast<const float4*>(segfea + (size_t)base * 4 * 256);
#pragma unroll
        for (int it = 0; it < 16; ++it) {
            int e4 = it * 256 + t;            // float4 index in the 64x256 tile
            float4 v4 = gsrc[e4];
            int r = e4 >> 6;                  // row
            int k0 = (e4 & 63) * 4;           // col (4-aligned)
            int idx = (((k0 >> 5) * 64 + r) * 4 + ((k0 >> 3) & 3)) * 8 + (k0 & 7);
            ushort4 u4;
            u4.x = bfr(v4.x); u4.y = bfr(v4.y); u4.z = bfr(v4.z); u4.w = bfr(v4.w);
            *reinterpret_cast<ushort4*>(x_lds + idx) = u4;
        }
    }
    if (t < 16) invs[t] = rank[keys[base + t]];
    __syncthreads();

    f32x4 acc[4][4];
    const f32x4 zz = {0.f, 0.f, 0.f, 0.f};

    // ================= K projection: [64x256] = X @ Wk =================
#pragma unroll
    for (int mt = 0; mt < 4; ++mt)
#pragma unroll
        for (int nt = 0; nt < 4; ++nt) acc[mt][nt] = zz;
#pragma unroll
    for (int kt = 0; kt < 8; ++kt) {
        bf16x8 b[4], a[4];
        const unsigned short* bp = wkf + (size_t)(((kt * 16 + w * 4) * 4 + quad) * 16 + c16) * 8;
        const unsigned short* ap = x_lds + ((kt * 64 + c16) * 4 + quad) * 8;
#pragma unroll
        for (int nt = 0; nt < 4; ++nt) b[nt] = *reinterpret_cast<const bf16x8*>(bp + nt * 512);
#pragma unroll
        for (int mt = 0; mt < 4; ++mt) a[mt] = *reinterpret_cast<const bf16x8*>(ap + mt * 512);
#pragma unroll
        for (int mt = 0; mt < 4; ++mt)
#pragma unroll
            for (int nt = 0; nt < 4; ++nt)
                acc[mt][nt] = __builtin_amdgcn_mfma_f32_16x16x32_bf16(a[mt], b[nt], acc[mt][nt], 0, 0, 0);
    }

    // ---- scores: s[p][l] = (K[p*4+l]+bk) . q[p]  (head w cols only)
    float bkv[4], qv[4][4];
#pragma unroll
    for (int nt = 0; nt < 4; ++nt) bkv[nt] = bk[w * 64 + nt * 16 + c16];
#pragma unroll
    for (int mt = 0; mt < 4; ++mt)
#pragma unroll
        for (int nt = 0; nt < 4; ++nt)
            qv[mt][nt] = fbf(q_in[(size_t)(base + mt * 4 + quad) * 256 + w * 64 + nt * 16 + c16]);

    float sc[4][4];   // [mt][l]
#pragma unroll
    for (int mt = 0; mt < 4; ++mt) {
#pragma unroll
        for (int r = 0; r < 4; ++r) sc[mt][r] = 0.f;
#pragma unroll
        for (int nt = 0; nt < 4; ++nt)
#pragma unroll
            for (int r = 0; r < 4; ++r)
                sc[mt][r] += (acc[mt][nt][r] + bkv[nt]) * qv[mt][nt];
    }
#pragma unroll
    for (int off = 1; off < 16; off <<= 1)
#pragma unroll
        for (int mt = 0; mt < 4; ++mt)
#pragma unroll
            for (int r = 0; r < 4; ++r) sc[mt][r] += __shfl_xor(sc[mt][r], off);

    // ---- softmax over l (exact, L=4), scale 1/sqrt(64)
    float aw[4][4];
#pragma unroll
    for (int mt = 0; mt < 4; ++mt) {
        float mx = -INFINITY;
#pragma unroll
        for (int r = 0; r < 4; ++r) { sc[mt][r] *= 0.125f; mx = fmaxf(mx, sc[mt][r]); }
        float s = 0.f;
#pragma unroll
        for (int r = 0; r < 4; ++r) { float e = __expf(sc[mt][r] - mx); aw[mt][r] = e; s += e; }
        float inv = 1.f / s;
#pragma unroll
        for (int r = 0; r < 4; ++r) aw[mt][r] *= inv;
    }

    // ================= V projection =================
#pragma unroll
    for (int mt = 0; mt < 4; ++mt)
#pragma unroll
        for (int nt = 0; nt < 4; ++nt) acc[mt][nt] = zz;
#pragma unroll
    for (int kt = 0; kt < 8; ++kt) {
        bf16x8 b[4], a[4];
        const unsigned short* bp = wvf + (size_t)(((kt * 16 + w * 4) * 4 + quad) * 16 + c16) * 8;
        const unsigned short* ap = x_lds + ((kt * 64 + c16) * 4 + quad) * 8;
#pragma unroll
        for (int nt = 0; nt < 4; ++nt) b[nt] = *reinterpret_cast<const bf16x8*>(bp + nt * 512);
#pragma unroll
        for (int mt = 0; mt < 4; ++mt) a[mt] = *reinterpret_cast<const bf16x8*>(ap + mt * 512);
#pragma unroll
        for (int mt = 0; mt < 4; ++mt)
#pragma unroll
            for (int nt = 0; nt < 4; ++nt)
                acc[mt][nt] = __builtin_amdgcn_mfma_f32_16x16x32_bf16(a[mt], b[nt], acc[mt][nt], 0, 0, 0);
    }

    // ---- attn . V -> attnv[p][d] (head w slice), write bf16 A-frag layout to LDS
    float bvv[4];
#pragma unroll
    for (int nt = 0; nt < 4; ++nt) bvv[nt] = bv[w * 64 + nt * 16 + c16];
#pragma unroll
    for (int mt = 0; mt < 4; ++mt) {
#pragma unroll
        for (int nt = 0; nt < 4; ++nt) {
            float o = bvv[nt];
#pragma unroll
            for (int r = 0; r < 4; ++r) o += aw[mt][r] * acc[mt][nt][r];
            int p = mt * 4 + quad;
            int d = w * 64 + nt * 16 + c16;
            int idx = (((d >> 5) * 16 + p) * 4 + ((d >> 3) & 3)) * 8 + (d & 7);
            av_lds[idx] = bfr(o);
        }
    }
    __syncthreads();

    // ================= Wo projection: [16x256] = attnv @ Wo =================
    f32x4 acc3[4];
#pragma unroll
    for (int nt = 0; nt < 4; ++nt) acc3[nt] = zz;
#pragma unroll
    for (int kt = 0; kt < 8; ++kt) {
        bf16x8 a = *reinterpret_cast<const bf16x8*>(av_lds + ((kt * 16 + c16) * 4 + quad) * 8);
        const unsigned short* bp = wof + (size_t)(((kt * 16 + w * 4) * 4 + quad) * 16 + c16) * 8;
#pragma unroll
        for (int nt = 0; nt < 4; ++nt) {
            bf16x8 b = *reinterpret_cast<const bf16x8*>(bp + nt * 512);
            acc3[nt] = __builtin_amdgcn_mfma_f32_16x16x32_bf16(a, b, acc3[nt], 0, 0, 0);
        }
    }
    // ---- sam + segment-max atomics
#pragma unroll
    for (int nt = 0; nt < 4; ++nt) {
        float bov = bo[w * 64 + nt * 16 + c16];
#pragma unroll
        for (int r = 0; r < 4; ++r) {
            int p = quad * 4 + r;
            float sam = acc3[nt][r] + bov;
            atomicMax(seg_u + (size_t)invs[p] * 256 + w * 64 + nt * 16 + c16, fenc(sam));
        }
    }
}

// ---------- KC2: decode seg/pix pooled regions in place -------------------------
__global__ void kC2(unsigned* __restrict__ seg_u, unsigned* __restrict__ pix_u,
                    const int* __restrict__ total)
{
    size_t idx = (size_t)blockIdx.x * 256 + threadIdx.x;
    const size_t SEG = (size_t)NPTS * 256;
    int tot = total[0];
    unsigned* buf = (idx < SEG) ? seg_u : pix_u;
    size_t k = (idx < SEG) ? idx : (idx - SEG);
    int j = (int)(k >> 8);
    if (j < tot) buf[k] = __float_as_uint(fdec(buf[k]));
}

extern "C" void kernel_launch(void* const* d_in, const int* in_sizes, int n_in,
                              void* d_out, int out_size, void* d_ws, size_t ws_size,
                              hipStream_t stream)
{
    const float* pt_fea = (const float*)d_in[0];
    const int*   xy     = (const int*)d_in[1];
    const float* segfea = (const float*)d_in[2];
    const float* pixfea = (const float*)d_in[3];
    const float* g0 = (const float*)d_in[4],  *b0 = (const float*)d_in[5];
    const float* m0 = (const float*)d_in[6],  *v0 = (const float*)d_in[7];
    const float* g1 = (const float*)d_in[8],  *bb1 = (const float*)d_in[9];
    const float* m1 = (const float*)d_in[10], *v1 = (const float*)d_in[11];
    const float* g2 = (const float*)d_in[12], *bb2 = (const float*)d_in[13];
    const float* m2 = (const float*)d_in[14], *v2 = (const float*)d_in[15];
    const float* g3 = (const float*)d_in[16], *bb3 = (const float*)d_in[17];
    const float* m3 = (const float*)d_in[18], *v3 = (const float*)d_in[19];
    const float* W1 = (const float*)d_in[20], *b1 = (const float*)d_in[21];
    const float* W2 = (const float*)d_in[22], *b2 = (const float*)d_in[23];
    const float* W3 = (const float*)d_in[24], *b3 = (const float*)d_in[25];
    const float* W4 = (const float*)d_in[26], *b4 = (const float*)d_in[27];
    const float* Wq = (const float*)d_in[28], *bq = (const float*)d_in[29];
    const float* Wk = (const float*)d_in[30], *bk = (const float*)d_in[31];
    const float* Wv = (const float*)d_in[32], *bv = (const float*)d_in[33];
    const float* Wo = (const float*)d_in[34], *bo = (const float*)d_in[35];
    const float* W128 = (const float*)d_in[36], *b128 = (const float*)d_in[37];
    const float* Wc = (const float*)d_in[38], *bc = (const float*)d_in[39];

    // d_out layout: unq[N,3] processed[N,16] seg_pooled[N,256] pix_pooled[N,256] unq_inv[N]
    float* out = (float*)d_out;
    float* out_unq  = out;
    float* out_proc = out + (size_t)NPTS * 3;
    unsigned* seg_u = (unsigned*)(out + (size_t)NPTS * 19);
    unsigned* pix_u = (unsigned*)(out + (size_t)NPTS * 275);
    float* out_inv  = out + (size_t)NPTS * 531;

    // ws layout: wf (3x65536 bf16, 16B-aligned), q bf16 [N*256], ints
    char* ws = (char*)d_ws;
    unsigned short* wf   = (unsigned short*)ws;
    unsigned short* q_bf = (unsigned short*)(ws + 3 * 65536 * 2);
    int* keys  = (int*)(ws + 3 * 65536 * 2 + (size_t)NPTS * 256 * 2);
    int* rank  = keys + NPTS;
    int* count = rank + NBINS;
    int* unqk  = count + NBINS;
    int* total = unqk + NPTS;

    const int NB16 = NPTS / 16;                      // 6250
    const size_t ZTOT = 2 * (size_t)NPTS * 256 + NBINS;
    kZ<<<(int)((ZTOT + 255) / 256), 256, 0, stream>>>(seg_u, pix_u, count);
    kH<<<(NPTS + 255) / 256, 256, 0, stream>>>(xy, keys, count);
    kScan<<<1, 1024, 0, stream>>>(count, rank, unqk, total);
    kU<<<(NPTS + 255) / 256, 256, 0, stream>>>(unqk, total, out_unq);
    kConv<<<768, 256, 0, stream>>>(Wk, Wv, Wo, wf);
    kA<<<NB16, 256, 0, stream>>>(pt_fea, keys, rank,
        g0, b0, m0, v0,
        W1, b1, g1, bb1, m1, v1,
        W2, b2, g2, bb2, m2, v2,
        W3, b3, g3, bb3, m3, v3,
        W4, b4, Wq, bq, q_bf, seg_u);
    kC1<<<NB16, 256, 0, stream>>>(seg_u, total, W128, b128, Wc, bc, out_proc);
    kP<<<NPTS, 256, 0, stream>>>(pixfea, keys, rank, pix_u, out_inv);
    kB<<<NB16, 256, 0, stream>>>(segfea, q_bf, keys, rank,
        wf, wf + 65536, wf + 131072, bk, bv, bo, seg_u);
    kC2<<<2 * NPTS, 256, 0, stream>>>(seg_u, pix_u, total);
}

// Round 3
// 1665.165 us; speedup vs baseline: 10.8495x; 3.1951x over previous
//
#include <hip/hip_runtime.h>
#include <math.h>

#define NPTS 100000
#define LKV 4
#define GYV 200
#define NBINS 40000   // GY*GY

typedef __attribute__((ext_vector_type(8))) short bf16x8;
typedef __attribute__((ext_vector_type(4))) float f32x4;

// ---------- bf16 helpers (RNE) --------------------------------------------------
__device__ __forceinline__ unsigned short bfr(float f) {
    unsigned u = __float_as_uint(f);
    unsigned r = (u + 0x7fffu + ((u >> 16) & 1u)) >> 16;
    return (unsigned short)r;
}
__device__ __forceinline__ float fbf(unsigned short h) {
    return __uint_as_float(((unsigned)h) << 16);
}

// ---------- monotonic float<->uint encoding for atomicMax-based segment max ----
__device__ __forceinline__ unsigned fenc(float f) {
    unsigned u = __float_as_uint(f);
    return (u & 0x80000000u) ? ~u : (u | 0x80000000u);
}
__device__ __forceinline__ float fdec(unsigned u) {
    unsigned b = (u & 0x80000000u) ? (u & 0x7fffffffu) : ~u;
    return __uint_as_float(b);
}

// ---------- tile GEMM (fp32 VALU; still used by kC1) ----------------------------
template <int KD, int OD, int MODE, bool OB = false>
__device__ __forceinline__ void tile_gemm(
    const float* __restrict__ W, const float* __restrict__ lb,
    const float* __restrict__ g, const float* __restrict__ bb,
    const float* __restrict__ m, const float* __restrict__ v,
    const float* __restrict__ in, void* outv, int t)
{
    constexpr int OPT = OD / 16;
    const int p = t >> 4, c = t & 15, o0 = c * OPT;
    const float* inp = in + p * KD;
    float acc[OPT];
#pragma unroll
    for (int j = 0; j < OPT; ++j) acc[j] = 0.f;
#pragma unroll 4
    for (int k = 0; k < KD; ++k) {
        float a = inp[k];
        const float* wr = W + k * OD + o0;
        if constexpr (OPT % 4 == 0) {
#pragma unroll
            for (int j4 = 0; j4 < OPT / 4; ++j4) {
                float4 w4 = reinterpret_cast<const float4*>(wr)[j4];
                acc[j4 * 4 + 0] += a * w4.x;
                acc[j4 * 4 + 1] += a * w4.y;
                acc[j4 * 4 + 2] += a * w4.z;
                acc[j4 * 4 + 3] += a * w4.w;
            }
        } else {
#pragma unroll
            for (int j = 0; j < OPT; ++j) acc[j] += a * wr[j];
        }
    }
#pragma unroll
    for (int j = 0; j < OPT; ++j) {
        int o = o0 + j;
        float y = acc[j] + lb[o];
        if constexpr (MODE == 1) {
            float s = g[o] * rsqrtf(v[o] + 1e-5f);
            y = (y - m[o]) * s + bb[o];
            y = fmaxf(y, 0.f);
        } else if constexpr (MODE == 2) {
            y = fmaxf(y, 0.f);
        }
        if constexpr (OB) ((unsigned short*)outv)[p * OD + o] = bfr(y);
        else              ((float*)outv)[p * OD + o] = y;
    }
}

// ---------- K0: zero seg/pix pool regions (as uint) + histogram bins ------------
__global__ void kZ(unsigned* __restrict__ seg_u, unsigned* __restrict__ pix_u,
                   int* __restrict__ count)
{
    size_t idx = (size_t)blockIdx.x * 256 + threadIdx.x;
    const size_t SEG = (size_t)NPTS * 256;
    if (idx < SEG)            seg_u[idx] = 0u;
    else if (idx < 2 * SEG)   pix_u[idx - SEG] = 0u;
    else if (idx < 2 * SEG + NBINS) count[idx - 2 * SEG] = 0;
}

// ---------- K1: keys + histogram ------------------------------------------------
__global__ void kH(const int* __restrict__ xy, int* __restrict__ keys,
                   int* __restrict__ count)
{
    int i = blockIdx.x * 256 + threadIdx.x;
    if (i < NPTS) {
        int key = xy[i * 2] * GYV + xy[i * 2 + 1];
        keys[i] = key;
        atomicAdd(count + key, 1);
    }
}

// ---------- K2: prefix-scan of present flags over 40000 bins (1 block) ----------
__global__ __launch_bounds__(1024) void kScan(
    const int* __restrict__ count, int* __restrict__ rank,
    int* __restrict__ unqk, int* __restrict__ total)
{
    __shared__ int swcnt[16];
    __shared__ int carry_s;
    const int t = threadIdx.x, lane = t & 63, wid = t >> 6;
    if (t == 0) carry_s = 0;
    for (int chunk = 0; chunk < 40; ++chunk) {
        __syncthreads();
        int idx = chunk * 1024 + t;
        int pres = (idx < NBINS && count[idx] > 0) ? 1 : 0;
        unsigned long long mask = __ballot(pres);
        int lanepre = __popcll(mask & ((1ull << lane) - 1ull));
        if (lane == 0) swcnt[wid] = __popcll(mask);
        __syncthreads();
        if (t == 0) {
            int s = carry_s;
            for (int w = 0; w < 16; ++w) { int cn = swcnt[w]; swcnt[w] = s; s += cn; }
            carry_s = s;
        }
        __syncthreads();
        if (pres) { int e = swcnt[wid] + lanepre; rank[idx] = e; unqk[e] = idx; }
    }
    __syncthreads();
    if (t == 0) total[0] = carry_s;
}

// ---------- KU: unq output rows -------------------------------------------------
__global__ void kU(const int* __restrict__ unqk, const int* __restrict__ total,
                   float* __restrict__ out_unq)
{
    int j = blockIdx.x * 256 + threadIdx.x;
    if (j < NPTS) {
        int k = (j < total[0]) ? unqk[j] : NBINS;
        out_unq[j * 3 + 0] = 0.f;
        out_unq[j * 3 + 1] = (float)(k / GYV);
        out_unq[j * 3 + 2] = (float)(k % GYV);
    }
}

// ---------- KConvW: fp32 [KD,OD] weight -> bf16 B-fragment order ---------------
// element (k,n) -> ((((k>>5)*(OD/16) + (n>>4))*4 + ((k>>3)&3))*16 + (n&15))*8 + (k&7)
__global__ void kConvW(const float* __restrict__ W, unsigned short* __restrict__ dst,
                       int KD, int OD)
{
    int gid = blockIdx.x * 256 + threadIdx.x;
    if (gid >= KD * OD) return;
    int k = gid / OD, n = gid - k * OD;
    int idx = ((((k >> 5) * (OD >> 4) + (n >> 4)) * 4 + ((k >> 3) & 3)) * 16 + (n & 15)) * 8 + (k & 7);
    dst[idx] = bfr(W[gid]);
}

// ---------- MFMA accumulate: A-frag LDS [64 x KD] x B-frag global -> acc --------
// wave w owns n-tiles [w*NT, w*NT+NT); acc[mt][nt] = C tile (row mt*16.., col tile)
template <int KD, int NTILES_TOT, int NT>
__device__ __forceinline__ void mfma_acc(
    const unsigned short* __restrict__ inbuf, const unsigned short* __restrict__ wf,
    int w, int quad, int c16, f32x4 (&acc)[4][NT])
{
    constexpr int KT = KD / 32;
    const f32x4 zz = {0.f, 0.f, 0.f, 0.f};
#pragma unroll
    for (int mt = 0; mt < 4; ++mt)
#pragma unroll
        for (int nt = 0; nt < NT; ++nt) acc[mt][nt] = zz;
#pragma unroll
    for (int kt = 0; kt < KT; ++kt) {
        bf16x8 a[4], b[NT];
        const unsigned short* ap = inbuf + ((kt * 64 + c16) * 4 + quad) * 8;
#pragma unroll
        for (int mt = 0; mt < 4; ++mt) a[mt] = *reinterpret_cast<const bf16x8*>(ap + mt * 512);
#pragma unroll
        for (int nt = 0; nt < NT; ++nt) {
            const unsigned short* bp = wf +
                (size_t)(((kt * NTILES_TOT + w * NT + nt) * 4 + quad) * 16 + c16) * 8;
            b[nt] = *reinterpret_cast<const bf16x8*>(bp);
        }
#pragma unroll
        for (int mt = 0; mt < 4; ++mt)
#pragma unroll
            for (int nt = 0; nt < NT; ++nt)
                acc[mt][nt] = __builtin_amdgcn_mfma_f32_16x16x32_bf16(a[mt], b[nt], acc[mt][nt], 0, 0, 0);
    }
}

// BN+ReLU epilogue -> bf16 A-frag LDS for next layer
template <int NT>
__device__ __forceinline__ void epi_bn(
    f32x4 (&acc)[4][NT], const float* lb, const float* g, const float* bb,
    const float* m, const float* v, unsigned short* __restrict__ outbuf,
    int w, int quad, int c16)
{
#pragma unroll
    for (int nt = 0; nt < NT; ++nt) {
        int n = (w * NT + nt) * 16 + c16;
        float sc = g[n] * rsqrtf(v[n] + 1e-5f);
        float mb = m[n], bbv = bb[n], lbv = lb[n];
        int nbase = ((n >> 5) * 64) * 32 + ((n >> 3) & 3) * 8 + (n & 7);
#pragma unroll
        for (int mt = 0; mt < 4; ++mt)
#pragma unroll
            for (int r = 0; r < 4; ++r) {
                int row = mt * 16 + quad * 4 + r;
                float y = fmaxf((acc[mt][nt][r] + lbv - mb) * sc + bbv, 0.f);
                outbuf[nbase + row * 32] = bfr(y);
            }
    }
}

// ---------- KA: PPmodel via MFMA + mlp pool-atomics + q (bf16) ------------------
// block = 64 points, 4 waves; ping-pong A-frag buffers.
__global__ __launch_bounds__(256) void kA(
    const float* __restrict__ pt_fea,
    const int* __restrict__ keys, const int* __restrict__ rank,
    const float* g0, const float* b0, const float* m0, const float* v0,
    const float* W1, const float* b1, const float* g1, const float* bb1, const float* m1, const float* v1,
    const unsigned short* __restrict__ w2f, const float* b2, const float* g2, const float* bb2, const float* m2, const float* v2,
    const unsigned short* __restrict__ w3f, const float* b3, const float* g3, const float* bb3, const float* m3, const float* v3,
    const unsigned short* __restrict__ w4f, const float* b4,
    const unsigned short* __restrict__ wqf, const float* bq,
    unsigned short* __restrict__ q_out, unsigned* __restrict__ seg_u)
{
    __shared__ __attribute__((aligned(16))) unsigned short bufX[64 * 256]; // 32 KB
    __shared__ __attribute__((aligned(16))) unsigned short bufY[64 * 256]; // 32 KB
    __shared__ float ptl[64 * 3];
    __shared__ int invs[64];
    const int t = threadIdx.x, w = t >> 6, lane = t & 63;
    const int quad = lane >> 4, c16 = lane & 15;
    const int base = blockIdx.x * 64;

    if (t < 192) {   // stage pt_fea + input BN
        int p = t / 3, c = t - p * 3;
        int gp = base + p; if (gp >= NPTS) gp = NPTS - 1;
        float x = pt_fea[gp * 3 + c];
        float s = g0[c] * rsqrtf(v0[c] + 1e-5f);
        ptl[t] = (x - m0[c]) * s + b0[c];
    }
    if (t < 64 && base + t < NPTS) invs[t] = rank[keys[base + t]];
    __syncthreads();

    // ---- layer1: 3 -> 64 (fp32 VALU) -> bufX A-frag
    {
        int p = t >> 2, o0 = (t & 3) * 16;
        float x0 = ptl[p * 3], x1 = ptl[p * 3 + 1], x2 = ptl[p * 3 + 2];
#pragma unroll
        for (int j = 0; j < 16; ++j) {
            int o = o0 + j;
            float y = x0 * W1[o] + x1 * W1[64 + o] + x2 * W1[128 + o] + b1[o];
            float s = g1[o] * rsqrtf(v1[o] + 1e-5f);
            y = fmaxf((y - m1[o]) * s + bb1[o], 0.f);
            int idx = ((o >> 5) * 64 + p) * 32 + ((o >> 3) & 3) * 8 + (o & 7);
            bufX[idx] = bfr(y);
        }
    }
    __syncthreads();

    // ---- layer2: 64 -> 128
    {
        f32x4 acc[4][2];
        mfma_acc<64, 8, 2>(bufX, w2f, w, quad, c16, acc);
        epi_bn<2>(acc, b2, g2, bb2, m2, v2, bufY, w, quad, c16);
    }
    __syncthreads();

    // ---- layer3: 128 -> 256
    {
        f32x4 acc[4][4];
        mfma_acc<128, 16, 4>(bufY, w3f, w, quad, c16, acc);
        epi_bn<4>(acc, b3, g3, bb3, m3, v3, bufX, w, quad, c16);
    }
    __syncthreads();

    // ---- layer4 (mlp): 256 -> 256, atomics + bf16 A-frag for Wq
    {
        f32x4 acc[4][4];
        mfma_acc<256, 16, 4>(bufX, w4f, w, quad, c16, acc);
#pragma unroll
        for (int nt = 0; nt < 4; ++nt) {
            int n = (w * 4 + nt) * 16 + c16;
            float lbv = b4[n];
            int nbase = ((n >> 5) * 64) * 32 + ((n >> 3) & 3) * 8 + (n & 7);
#pragma unroll
            for (int mt = 0; mt < 4; ++mt)
#pragma unroll
                for (int r = 0; r < 4; ++r) {
                    int row = mt * 16 + quad * 4 + r;
                    float y = acc[mt][nt][r] + lbv;
                    bufY[nbase + row * 32] = bfr(y);
                    if (base + row < NPTS)
                        atomicMax(seg_u + (size_t)invs[row] * 256 + n, fenc(y));
                }
        }
    }
    __syncthreads();

    // ---- q = mlp @ Wq + bq -> global bf16
    {
        f32x4 acc[4][4];
        mfma_acc<256, 16, 4>(bufY, wqf, w, quad, c16, acc);
#pragma unroll
        for (int nt = 0; nt < 4; ++nt) {
            int n = (w * 4 + nt) * 16 + c16;
            float lbv = bq[n];
#pragma unroll
            for (int mt = 0; mt < 4; ++mt)
#pragma unroll
                for (int r = 0; r < 4; ++r) {
                    int row = mt * 16 + quad * 4 + r;
                    if (base + row < NPTS)
                        q_out[(size_t)(base + row) * 256 + n] = bfr(acc[mt][nt][r] + lbv);
                }
        }
    }
}

// ---------- KC1: decode pooled-mlp, compression head, re-zero region ------------
__global__ __launch_bounds__(256) void kC1(
    unsigned* __restrict__ seg_u, const int* __restrict__ total,
    const float* __restrict__ W128, const float* __restrict__ b128,
    const float* __restrict__ Wc, const float* __restrict__ bc,
    float* __restrict__ out_proc)
{
    __shared__ float pooled[16 * 256];
    __shared__ float ori[16 * 128];
    const int t = threadIdx.x, p = t >> 4, c = t & 15;
    const int j0 = blockIdx.x * 16;
    const int tot = total[0];
    {
        const int j = j0 + p;
        unsigned* src = seg_u + (size_t)j * 256 + c * 16;
        float* dst = pooled + p * 256 + c * 16;
        if (j < tot) {
#pragma unroll
            for (int jj = 0; jj < 16; ++jj) { dst[jj] = fdec(src[jj]); src[jj] = 0u; }
        } else {
#pragma unroll
            for (int jj = 0; jj < 16; ++jj) dst[jj] = 0.f;
        }
    }
    __syncthreads();
    tile_gemm<256, 128, 0>(W128, b128, nullptr, nullptr, nullptr, nullptr, pooled, ori, t);
    __syncthreads();
    tile_gemm<128, 16, 2>(Wc, bc, nullptr, nullptr, nullptr, nullptr,
                          ori, out_proc + (size_t)j0 * 16, t);
}

// ---------- KP: pix pool atomics + unq_inv output -------------------------------
__global__ void kP(const float* __restrict__ pixfea,
                   const int* __restrict__ keys, const int* __restrict__ rank,
                   unsigned* __restrict__ pix_u, float* __restrict__ out_inv)
{
    size_t idx = (size_t)blockIdx.x * 256 + threadIdx.x;
    int i = (int)(idx >> 8), c = (int)(idx & 255);
    int inv = rank[keys[i]];
    atomicMax(pix_u + (size_t)inv * 256 + c, fenc(pixfea[idx]));
    if (c == 0) out_inv[i] = (float)inv;
}

// ---------- KB: bf16-MFMA fused MHA + sam pool atomics --------------------------
__global__ __launch_bounds__(256) void kB(
    const float* __restrict__ segfea, const unsigned short* __restrict__ q_in,
    const int* __restrict__ keys, const int* __restrict__ rank,
    const unsigned short* __restrict__ wkf, const unsigned short* __restrict__ wvf,
    const unsigned short* __restrict__ wof,
    const float* __restrict__ bk, const float* __restrict__ bv,
    const float* __restrict__ bo,
    unsigned* __restrict__ seg_u)
{
    __shared__ __attribute__((aligned(16))) unsigned short x_lds[64 * 256];   // 32 KB
    __shared__ __attribute__((aligned(16))) unsigned short av_lds[16 * 256];  // 8 KB
    __shared__ int invs[16];
    const int t = threadIdx.x, w = t >> 6, lane = t & 63;
    const int quad = lane >> 4, c16 = lane & 15;
    const int base = blockIdx.x * 16;

    {
        const float4* gsrc = reinterpret_cast<const float4*>(segfea + (size_t)base * 4 * 256);
#pragma unroll
        for (int it = 0; it < 16; ++it) {
            int e4 = it * 256 + t;
            float4 v4 = gsrc[e4];
            int r = e4 >> 6;
            int k0 = (e4 & 63) * 4;
            int idx = (((k0 >> 5) * 64 + r) * 4 + ((k0 >> 3) & 3)) * 8 + (k0 & 7);
            ushort4 u4;
            u4.x = bfr(v4.x); u4.y = bfr(v4.y); u4.z = bfr(v4.z); u4.w = bfr(v4.w);
            *reinterpret_cast<ushort4*>(x_lds + idx) = u4;
        }
    }
    if (t < 16) invs[t] = rank[keys[base + t]];
    __syncthreads();

    f32x4 acc[4][4];
    const f32x4 zz = {0.f, 0.f, 0.f, 0.f};

    // ================= K projection =================
    mfma_acc<256, 16, 4>(x_lds, wkf, w, quad, c16, acc);

    float bkv[4], qv[4][4];
#pragma unroll
    for (int nt = 0; nt < 4; ++nt) bkv[nt] = bk[w * 64 + nt * 16 + c16];
#pragma unroll
    for (int mt = 0; mt < 4; ++mt)
#pragma unroll
        for (int nt = 0; nt < 4; ++nt)
            qv[mt][nt] = fbf(q_in[(size_t)(base + mt * 4 + quad) * 256 + w * 64 + nt * 16 + c16]);

    float sc[4][4];
#pragma unroll
    for (int mt = 0; mt < 4; ++mt) {
#pragma unroll
        for (int r = 0; r < 4; ++r) sc[mt][r] = 0.f;
#pragma unroll
        for (int nt = 0; nt < 4; ++nt)
#pragma unroll
            for (int r = 0; r < 4; ++r)
                sc[mt][r] += (acc[mt][nt][r] + bkv[nt]) * qv[mt][nt];
    }
#pragma unroll
    for (int off = 1; off < 16; off <<= 1)
#pragma unroll
        for (int mt = 0; mt < 4; ++mt)
#pragma unroll
            for (int r = 0; r < 4; ++r) sc[mt][r] += __shfl_xor(sc[mt][r], off);

    float aw[4][4];
#pragma unroll
    for (int mt = 0; mt < 4; ++mt) {
        float mx = -INFINITY;
#pragma unroll
        for (int r = 0; r < 4; ++r) { sc[mt][r] *= 0.125f; mx = fmaxf(mx, sc[mt][r]); }
        float s = 0.f;
#pragma unroll
        for (int r = 0; r < 4; ++r) { float e = __expf(sc[mt][r] - mx); aw[mt][r] = e; s += e; }
        float inv = 1.f / s;
#pragma unroll
        for (int r = 0; r < 4; ++r) aw[mt][r] *= inv;
    }

    // ================= V projection =================
    mfma_acc<256, 16, 4>(x_lds, wvf, w, quad, c16, acc);

    float bvv[4];
#pragma unroll
    for (int nt = 0; nt < 4; ++nt) bvv[nt] = bv[w * 64 + nt * 16 + c16];
#pragma unroll
    for (int mt = 0; mt < 4; ++mt) {
#pragma unroll
        for (int nt = 0; nt < 4; ++nt) {
            float o = bvv[nt];
#pragma unroll
            for (int r = 0; r < 4; ++r) o += aw[mt][r] * acc[mt][nt][r];
            int p = mt * 4 + quad;
            int d = w * 64 + nt * 16 + c16;
            int idx = (((d >> 5) * 16 + p) * 4 + ((d >> 3) & 3)) * 8 + (d & 7);
            av_lds[idx] = bfr(o);
        }
    }
    __syncthreads();

    // ================= Wo projection =================
    f32x4 acc3[4];
#pragma unroll
    for (int nt = 0; nt < 4; ++nt) acc3[nt] = zz;
#pragma unroll
    for (int kt = 0; kt < 8; ++kt) {
        bf16x8 a = *reinterpret_cast<const bf16x8*>(av_lds + ((kt * 16 + c16) * 4 + quad) * 8);
        const unsigned short* bp = wof + (size_t)(((kt * 16 + w * 4) * 4 + quad) * 16 + c16) * 8;
#pragma unroll
        for (int nt = 0; nt < 4; ++nt) {
            bf16x8 b = *reinterpret_cast<const bf16x8*>(bp + nt * 512);
            acc3[nt] = __builtin_amdgcn_mfma_f32_16x16x32_bf16(a, b, acc3[nt], 0, 0, 0);
        }
    }
#pragma unroll
    for (int nt = 0; nt < 4; ++nt) {
        float bov = bo[w * 64 + nt * 16 + c16];
#pragma unroll
        for (int r = 0; r < 4; ++r) {
            int p = quad * 4 + r;
            float sam = acc3[nt][r] + bov;
            atomicMax(seg_u + (size_t)invs[p] * 256 + w * 64 + nt * 16 + c16, fenc(sam));
        }
    }
}

// ---------- KC2: decode seg/pix pooled regions in place -------------------------
__global__ void kC2(unsigned* __restrict__ seg_u, unsigned* __restrict__ pix_u,
                    const int* __restrict__ total)
{
    size_t idx = (size_t)blockIdx.x * 256 + threadIdx.x;
    const size_t SEG = (size_t)NPTS * 256;
    int tot = total[0];
    unsigned* buf = (idx < SEG) ? seg_u : pix_u;
    size_t k = (idx < SEG) ? idx : (idx - SEG);
    int j = (int)(k >> 8);
    if (j < tot) buf[k] = __float_as_uint(fdec(buf[k]));
}

extern "C" void kernel_launch(void* const* d_in, const int* in_sizes, int n_in,
                              void* d_out, int out_size, void* d_ws, size_t ws_size,
                              hipStream_t stream)
{
    const float* pt_fea = (const float*)d_in[0];
    const int*   xy     = (const int*)d_in[1];
    const float* segfea = (const float*)d_in[2];
    const float* pixfea = (const float*)d_in[3];
    const float* g0 = (const float*)d_in[4],  *b0 = (const float*)d_in[5];
    const float* m0 = (const float*)d_in[6],  *v0 = (const float*)d_in[7];
    const float* g1 = (const float*)d_in[8],  *bb1 = (const float*)d_in[9];
    const float* m1 = (const float*)d_in[10], *v1 = (const float*)d_in[11];
    const float* g2 = (const float*)d_in[12], *bb2 = (const float*)d_in[13];
    const float* m2 = (const float*)d_in[14], *v2 = (const float*)d_in[15];
    const float* g3 = (const float*)d_in[16], *bb3 = (const float*)d_in[17];
    const float* m3 = (const float*)d_in[18], *v3 = (const float*)d_in[19];
    const float* W1 = (const float*)d_in[20], *b1 = (const float*)d_in[21];
    const float* W2 = (const float*)d_in[22], *b2 = (const float*)d_in[23];
    const float* W3 = (const float*)d_in[24], *b3 = (const float*)d_in[25];
    const float* W4 = (const float*)d_in[26], *b4 = (const float*)d_in[27];
    const float* Wq = (const float*)d_in[28], *bq = (const float*)d_in[29];
    const float* Wk = (const float*)d_in[30], *bk = (const float*)d_in[31];
    const float* Wv = (const float*)d_in[32], *bv = (const float*)d_in[33];
    const float* Wo = (const float*)d_in[34], *bo = (const float*)d_in[35];
    const float* W128 = (const float*)d_in[36], *b128 = (const float*)d_in[37];
    const float* Wc = (const float*)d_in[38], *bc = (const float*)d_in[39];

    // d_out layout: unq[N,3] processed[N,16] seg_pooled[N,256] pix_pooled[N,256] unq_inv[N]
    float* out = (float*)d_out;
    float* out_unq  = out;
    float* out_proc = out + (size_t)NPTS * 3;
    unsigned* seg_u = (unsigned*)(out + (size_t)NPTS * 19);
    unsigned* pix_u = (unsigned*)(out + (size_t)NPTS * 275);
    float* out_inv  = out + (size_t)NPTS * 531;

    // ws layout: wf (7 matrices bf16 frag-order), q bf16 [N*256], ints
    char* ws = (char*)d_ws;
    unsigned short* wf = (unsigned short*)ws;
    unsigned short* wkf = wf;                 // 65536
    unsigned short* wvf = wf + 65536;         // 65536
    unsigned short* wof = wf + 131072;        // 65536
    unsigned short* wqf = wf + 196608;        // 65536
    unsigned short* w4f = wf + 262144;        // 65536
    unsigned short* w3f = wf + 327680;        // 32768
    unsigned short* w2f = wf + 360448;        // 8192  -> total 368640
    unsigned short* q_bf = wf + 368640;
    int* keys  = (int*)(ws + (size_t)368640 * 2 + (size_t)NPTS * 256 * 2);
    int* rank  = keys + NPTS;
    int* count = rank + NBINS;
    int* unqk  = count + NBINS;
    int* total = unqk + NPTS;

    const int NB16 = NPTS / 16;                      // 6250
    const int NB64 = (NPTS + 63) / 64;               // 1563
    const size_t ZTOT = 2 * (size_t)NPTS * 256 + NBINS;
    kZ<<<(int)((ZTOT + 255) / 256), 256, 0, stream>>>(seg_u, pix_u, count);
    kH<<<(NPTS + 255) / 256, 256, 0, stream>>>(xy, keys, count);
    kScan<<<1, 1024, 0, stream>>>(count, rank, unqk, total);
    kU<<<(NPTS + 255) / 256, 256, 0, stream>>>(unqk, total, out_unq);
    kConvW<<<256, 256, 0, stream>>>(Wk, wkf, 256, 256);
    kConvW<<<256, 256, 0, stream>>>(Wv, wvf, 256, 256);
    kConvW<<<256, 256, 0, stream>>>(Wo, wof, 256, 256);
    kConvW<<<256, 256, 0, stream>>>(Wq, wqf, 256, 256);
    kConvW<<<256, 256, 0, stream>>>(W4, w4f, 256, 256);
    kConvW<<<128, 256, 0, stream>>>(W3, w3f, 128, 256);
    kConvW<<<32, 256, 0, stream>>>(W2, w2f, 64, 128);
    kA<<<NB64, 256, 0, stream>>>(pt_fea, keys, rank,
        g0, b0, m0, v0,
        W1, b1, g1, bb1, m1, v1,
        w2f, b2, g2, bb2, m2, v2,
        w3f, b3, g3, bb3, m3, v3,
        w4f, b4, wqf, bq, q_bf, seg_u);
    kC1<<<NB16, 256, 0, stream>>>(seg_u, total, W128, b128, Wc, bc, out_proc);
    kP<<<NPTS, 256, 0, stream>>>(pixfea, keys, rank, pix_u, out_inv);
    kB<<<NB16, 256, 0, stream>>>(segfea, q_bf, keys, rank,
        wkf, wvf, wof, bk, bv, bo, seg_u);
    kC2<<<2 * NPTS, 256, 0, stream>>>(seg_u, pix_u, total);
}